// Round 5
// baseline (244.079 us; speedup 1.0000x reference)
//
#include <hip/hip_runtime.h>
#include <math.h>

#define NC 19
#define NB 8
#define HW (512 * 512)
#define CHUNKS 32  // R5: 32 chunks x 5 groups x 8 batches = 1280 uniform blocks
#define NG 5       // channel quads {0-3},{4-7},{8-11},{12-15},{16,17,18,counts}
#define TPB 128
#define SROW 76    // v4f row: 19 classes x 4 floats; 304B-aligned; b128 at this
                   // stride = uniform 8 words/bank -> full LDS throughput
#define UNROLL 4   // software-pipeline batch: load 4 iters ahead
#define FT 1024
#define NBLK (NG * CHUNKS * NB)  // 1280; %8==0 -> bijective XCD swizzle

typedef float v4f __attribute__((ext_vector_type(4)));
typedef int v4i __attribute__((ext_vector_type(4)));

// R2: LDS atomics 5.5x slower than RMW -- keep RMW.
// R4: v2f packing (DS ops halved) was NEUTRAL -> accum not LDS-bound.
// R5: attack loaded BYTES: 4 channels per block amortize the tgt word over
// twice as many channels (tgt re-reads 84->42 MB, total vector traffic -17%),
// and the per-pixel LDS RMW becomes one b128 (DS ops halved again).

// Workspace: S_part[NB][CHUNKS][NC][20] floats (389,120 B), unique slot per
// (b,chunk,col) -> no zero-init, no atomics. Row t = class, col c in 0..18 =
// sum of channel c over class-t pixels, col 19 = class-t count.

__global__ __launch_bounds__(TPB) void accum_kernel(const float* __restrict__ seg,
                                                    const int* __restrict__ tgt,
                                                    float* __restrict__ S_part) {
    __shared__ float bins[TPB * SROW];  // 38,912 B -> 4 blocks/CU resident

    const int tid = threadIdx.x;

    // XCD-tile swizzle (R1, kept): the 5 groups sharing one tgt chunk land on
    // ONE XCD so the chunk is pulled into that L2 once.
    const int bid = blockIdx.x;
    const int L = (bid & 7) * (NBLK / 8) + (bid >> 3);  // bijective, 1280 % 8 == 0
    const int g = L % NG;
    const int tile = L / NG;
    const int chunk = tile % CHUNKS;
    const int b = tile / CHUNKS;

    const bool lastg = (g == NG - 1);
    const int c0 = 4 * g;

    v4f* pp = (v4f*)&bins[tid * SROW];  // pp[t] = {c0,c0+1,c0+2,c0+3-or-count}
    #pragma unroll
    for (int k = 0; k < NC; ++k) pp[k] = (v4f){0.0f, 0.0f, 0.0f, 0.0f};
    // Rows are thread-private until the fold: no barrier needed here.

    const int per_chunk = HW / CHUNKS;  // 8192 pixels
    const size_t pix = (size_t)chunk * per_chunk;
    const v4f* __restrict__ sA = (const v4f*)(seg + ((size_t)(b * NC + c0)) * HW + pix);
    const v4f* __restrict__ sB = (const v4f*)(seg + ((size_t)(b * NC + c0 + 1)) * HW + pix);
    const v4f* __restrict__ sC = (const v4f*)(seg + ((size_t)(b * NC + c0 + 2)) * HW + pix);
    // Last group: channel c0+3 == 19 doesn't exist (counts column). Alias the
    // pointer in-bounds; the value is replaced by `ones` below.
    const v4f* __restrict__ sD =
        (const v4f*)(seg + ((size_t)(b * NC + (lastg ? c0 : c0 + 3))) * HW + pix);
    const v4i* __restrict__ tv = (const v4i*)(tgt + (size_t)b * HW + pix);

    const int iters = per_chunk / 4 / TPB;   // 16
    const int nsuper = iters / UNROLL;       // 4 (even -> clean ping-pong)
    const v4f ones = {1.0f, 1.0f, 1.0f, 1.0f};

    // Cacheable loads on purpose: inputs are ~half L3-warm per replay (R2:
    // 82 MB HBM fetch); nt would forfeit the cached half.
    v4f A0[UNROLL], A1[UNROLL], A2[UNROLL], A3[UNROLL];
    v4f B0[UNROLL], B1[UNROLL], B2[UNROLL], B3[UNROLL];
    v4i TA[UNROLL], TB[UNROLL];

#define PREFETCH(T_, Z0, Z1, Z2, Z3, stage)                       \
    if ((stage) < nsuper) {                                       \
        const int base_ = (stage) * UNROLL * TPB + tid;           \
        _Pragma("unroll")                                         \
        for (int j = 0; j < UNROLL; ++j) {                        \
            const int v_ = base_ + j * TPB;                       \
            T_[j] = tv[v_];                                       \
            Z0[j] = sA[v_];                                       \
            Z1[j] = sB[v_];                                       \
            Z2[j] = sC[v_];                                       \
            Z3[j] = lastg ? ones : sD[v_];                        \
        }                                                         \
    }

#define CONSUME(T_, Z0, Z1, Z2, Z3)                               \
    _Pragma("unroll")                                             \
    for (int j = 0; j < UNROLL; ++j) {                            \
        const v4i t_ = T_[j];                                     \
        v4f u_;                                                   \
        u_.x = Z0[j].x; u_.y = Z1[j].x; u_.z = Z2[j].x; u_.w = Z3[j].x; pp[t_.x] += u_; \
        u_.x = Z0[j].y; u_.y = Z1[j].y; u_.z = Z2[j].y; u_.w = Z3[j].y; pp[t_.y] += u_; \
        u_.x = Z0[j].z; u_.y = Z1[j].z; u_.z = Z2[j].z; u_.w = Z3[j].z; pp[t_.z] += u_; \
        u_.x = Z0[j].w; u_.y = Z1[j].w; u_.z = Z2[j].w; u_.w = Z3[j].w; pp[t_.w] += u_; \
    }

    PREFETCH(TA, A0, A1, A2, A3, 0)
    for (int s = 0; s < nsuper; s += 2) {
        PREFETCH(TB, B0, B1, B2, B3, s + 1)
        CONSUME(TA, A0, A1, A2, A3)
        PREFETCH(TA, A0, A1, A2, A3, s + 2)
        CONSUME(TB, B0, B1, B2, B3)
    }
#undef PREFETCH
#undef CONSUME
    __syncthreads();

    // Stage 1: fold 128 rows -> 32 rows over the 76 live columns, in-place safe
    // (rows 0..31 written only by their owner after reading; rows >=32 read-only).
    for (int e = tid; e < 32 * SROW; e += TPB) {  // 2432 elements
        const int r = e & 31, c = e >> 5;  // c in 0..75
        float acc = bins[r * SROW + c];
        #pragma unroll
        for (int j = 1; j < TPB / 32; ++j) acc += bins[(r + 32 * j) * SROW + c];
        bins[r * SROW + c] = acc;
    }
    __syncthreads();

    // Stage 2: 76 lanes sum the 32 rows of their column; plain store.
    // Packed layout: col = 4*t + q -> channel c0+q; g==4,q==3 -> 19 = counts.
    if (tid < 4 * NC) {
        float acc = bins[tid];
        #pragma unroll
        for (int r = 1; r < 32; ++r) acc += bins[r * SROW + tid];
        const int t = tid >> 2;            // class
        const int c = c0 + (tid & 3);      // channel col (19 == counts)
        S_part[(((size_t)(b * CHUNKS + chunk)) * NC + t) * 20 + c] = acc;
    }
}

__global__ __launch_bounds__(FT) void finalize_kernel(const float* __restrict__ S_part,
                                                      float* __restrict__ out) {
    __shared__ float S[NB * NC * 20];  // 3040 floats: S[b][t][c], col 19 = count
    __shared__ float wsum[FT / 64];
    const int tid = threadIdx.x;

    // Phase A: reduce the 32 chunk partials (coalesced: r is contiguous).
    for (int e = tid; e < NB * NC * 20; e += FT) {
        const int b = e / (NC * 20);
        const int r = e - b * NC * 20;
        float a = 0.0f;
        #pragma unroll
        for (int ch = 0; ch < CHUNKS; ++ch)
            a += S_part[((size_t)(b * CHUNKS + ch)) * (NC * 20) + r];
        S[e] = a;
    }
    __syncthreads();

    // Phase B: 2888 log terms.
    const float eps = 2.220446049250313e-16f;  // np.spacing(1)
    float local = 0.0f;
    for (int idx = tid; idx < NB * NC * NC; idx += FT) {
        const int b = idx / (NC * NC);
        const int r = idx - b * NC * NC;
        const int i = r / NC;
        const int k = r - i * NC;
        const float* Sb = S + b * NC * 20;
        const float cnt_i = Sb[i * 20 + 19];
        const float cnt_k = Sb[k * 20 + 19];
        const float alpha = (cnt_i > 0.0f) ? Sb[i * 20 + i] / cnt_i : 0.0f;
        const float beta = (cnt_k > 0.0f) ? 1.0f - Sb[k * 20 + i] / cnt_k : 0.0f;
        local += logf(0.5f * (alpha + beta + eps));
    }

    #pragma unroll
    for (int off = 32; off > 0; off >>= 1) local += __shfl_down(local, off);
    if ((tid & 63) == 0) wsum[tid >> 6] = local;
    __syncthreads();
    if (tid == 0) {
        float t = 0.0f;
        #pragma unroll
        for (int w = 0; w < FT / 64; ++w) t += wsum[w];
        out[0] = -0.5f * t / (float)NB;
    }
}

extern "C" void kernel_launch(void* const* d_in, const int* in_sizes, int n_in,
                              void* d_out, int out_size, void* d_ws, size_t ws_size,
                              hipStream_t stream) {
    const float* seg = (const float*)d_in[0];
    const int* tgt = (const int*)d_in[1];
    float* S_part = (float*)d_ws;  // 389,120 B; every slot written unconditionally

    dim3 grid(NBLK);  // 1D; XCD-tile swizzle done in-kernel
    accum_kernel<<<grid, TPB, 0, stream>>>(seg, tgt, S_part);
    finalize_kernel<<<1, FT, 0, stream>>>(S_part, (float*)d_out);
}

// Round 6
// 233.008 us; speedup vs baseline: 1.0475x; 1.0475x over previous
//
#include <hip/hip_runtime.h>
#include <math.h>

#define NC 19
#define NB 8
#define HW (512 * 512)
#define CHUNKS 16
#define NG 10      // channel pairs {0,1},...,{16,17}, then {18, counts}
#define TPB 128    // 19.5 KB LDS -> 8 blocks/CU -> all 1280 blocks co-resident
#define SROW 38    // packed v2f row: 19 classes x 2 floats; even -> 8B-aligned b64,
                   // bank stride 6 mod 32 (gcd 2) -> free 2-way alias (m136)
#define UNROLL 4   // software-pipeline batch: load 4 iters ahead
#define FT 1024
#define NBLK (NG * CHUNKS * NB)  // 1280 blocks; 1280 % 8 == 0 -> bijective XCD swizzle

typedef float v4f __attribute__((ext_vector_type(4)));
typedef float v2f __attribute__((ext_vector_type(2)));
typedef int v4i __attribute__((ext_vector_type(4)));

// Probe ledger (all within-harness A/B, noise ~ +/-2 us):
//   R1 XCD-tile swizzle: -2.6 us (kept).  R2 ds_add_f32 LDS atomics: 5.5x
//   SLOWER (gfx950 LDS atomic-fadd has far lower throughput than pipelined
//   RMW -- reverted).  R3 TPB 256->128 (kill dispatch tail): neutral.
//   R4 v2f packing (DS ops halved): neutral -> accum not LDS/issue-bound.
//   R5 4-channel quads (-17% bytes): +11.5 us REGRESSION (4 blocks/CU -> only
//   1024/1280 resident -> second-round tail; reverted).
// Conclusion: accum ~30-33 us vs 26.7 us die-level floor (168 MB @ 6.3 TB/s);
// timed region is 81% harness fill restore. This config is the converged one.

// Workspace: S_part[NB][CHUNKS][NC][20] floats (194,560 B), unique slot per
// (b,chunk,col) -> no zero-init, no atomics. Row t = class, col c in 0..18 =
// sum of channel c over class-t pixels, col 19 = class-t count.

__global__ __launch_bounds__(TPB) void accum_kernel(const float* __restrict__ seg,
                                                    const int* __restrict__ tgt,
                                                    float* __restrict__ S_part) {
    __shared__ float bins[TPB * SROW];  // 19,456 B, per-thread-private rows

    const int tid = threadIdx.x;

    // XCD-tile swizzle (R1, kept): blocks sharing one tgt chunk land on ONE XCD.
    const int bid = blockIdx.x;
    const int L = (bid & 7) * (NBLK / 8) + (bid >> 3);  // bijective, 1280 % 8 == 0
    const int g = L % NG;
    const int tile = L / NG;
    const int chunk = tile & (CHUNKS - 1);
    const int b = tile >> 4;                             // CHUNKS == 16

    const bool last = (g == NG - 1);
    const int c0 = 2 * g;

    v2f* pp = (v2f*)&bins[tid * SROW];   // pp[t] = {sum_c0, sum_c1} for class t
    #pragma unroll
    for (int k = 0; k < NC; ++k) pp[k] = (v2f){0.0f, 0.0f};
    // Rows are thread-private until the fold: no barrier needed here.

    const int per_chunk = HW / CHUNKS;  // 16384 pixels
    const size_t pix = (size_t)chunk * per_chunk;
    const v4f* __restrict__ s0 = (const v4f*)(seg + ((size_t)(b * NC + c0)) * HW + pix);
    // Last group: alias s1 to s0 so every issued load is in-bounds even if the
    // compiler if-converts the select below (c0+1 == 19 would read past seg at b==7).
    const v4f* __restrict__ s1 =
        (const v4f*)(seg + ((size_t)(b * NC + (last ? c0 : c0 + 1))) * HW + pix);
    const v4i* __restrict__ tv = (const v4i*)(tgt + (size_t)b * HW + pix);

    const int iters = per_chunk / 4 / TPB;   // 32
    const int nsuper = iters / UNROLL;       // 8 (even -> clean ping-pong)
    const v4f ones = {1.0f, 1.0f, 1.0f, 1.0f};

    // Cacheable loads on purpose: inputs are ~half L3-warm per replay (R2:
    // 82 MB HBM fetch of 168 MB read); nt would forfeit the cached half.
    v4f A0[UNROLL], A1[UNROLL];
    v4f B0[UNROLL], B1[UNROLL];
    v4i TA[UNROLL], TB[UNROLL];

#define PREFETCH(T_, Z0, Z1, stage)                               \
    if ((stage) < nsuper) {                                       \
        const int base_ = (stage) * UNROLL * TPB + tid;           \
        _Pragma("unroll")                                         \
        for (int j = 0; j < UNROLL; ++j) {                        \
            const int v_ = base_ + j * TPB;                       \
            T_[j] = tv[v_];                                       \
            Z0[j] = s0[v_];                                       \
            Z1[j] = last ? ones : s1[v_];                         \
        }                                                         \
    }

#define CONSUME(T_, Z0, Z1)                                       \
    _Pragma("unroll")                                             \
    for (int j = 0; j < UNROLL; ++j) {                            \
        const v4i t_ = T_[j];                                     \
        v2f u_;                                                   \
        u_.x = Z0[j].x; u_.y = Z1[j].x; pp[t_.x] += u_;           \
        u_.x = Z0[j].y; u_.y = Z1[j].y; pp[t_.y] += u_;           \
        u_.x = Z0[j].z; u_.y = Z1[j].z; pp[t_.z] += u_;           \
        u_.x = Z0[j].w; u_.y = Z1[j].w; pp[t_.w] += u_;           \
    }

    PREFETCH(TA, A0, A1, 0)
    for (int s = 0; s < nsuper; s += 2) {
        PREFETCH(TB, B0, B1, s + 1)
        CONSUME(TA, A0, A1)
        PREFETCH(TA, A0, A1, s + 2)
        CONSUME(TB, B0, B1)
    }
#undef PREFETCH
#undef CONSUME
    __syncthreads();

    // Stage 1: fold 128 rows -> 32 rows over the 38 live columns, in-place safe
    // (rows 0..31 written only by their owner after reading; rows >=32 read-only).
    for (int e = tid; e < 32 * SROW; e += TPB) {  // 1216 elements
        const int r = e & 31, c = e >> 5;  // c in 0..37
        float acc = bins[r * SROW + c];
        #pragma unroll
        for (int j = 1; j < TPB / 32; ++j) acc += bins[(r + 32 * j) * SROW + c];
        bins[r * SROW + c] = acc;
    }
    __syncthreads();

    // Stage 2: 38 lanes (wave 0) sum the 32 rows of their column; plain store.
    // Packed layout: col = 2*t + half, half 0 -> channel c0, half 1 -> c0+1
    // (for g==9, c0+1 == 19 == the counts column).
    if (tid < 2 * NC) {
        float acc = bins[tid];
        #pragma unroll
        for (int r = 1; r < 32; ++r) acc += bins[r * SROW + tid];
        const int t = tid >> 1;            // class
        const int c = c0 + (tid & 1);      // channel col
        S_part[(((size_t)(b * CHUNKS + chunk)) * NC + t) * 20 + c] = acc;
    }
}

__global__ __launch_bounds__(FT) void finalize_kernel(const float* __restrict__ S_part,
                                                      float* __restrict__ out) {
    __shared__ float S[NB * NC * 20];  // 3040 floats: S[b][t][c], col 19 = count
    __shared__ float wsum[FT / 64];
    const int tid = threadIdx.x;

    // Phase A: reduce the 16 chunk partials (coalesced: r is contiguous).
    for (int e = tid; e < NB * NC * 20; e += FT) {
        const int b = e / (NC * 20);
        const int r = e - b * NC * 20;
        float a = 0.0f;
        #pragma unroll
        for (int ch = 0; ch < CHUNKS; ++ch)
            a += S_part[((size_t)(b * CHUNKS + ch)) * (NC * 20) + r];
        S[e] = a;
    }
    __syncthreads();

    // Phase B: 2888 log terms.
    const float eps = 2.220446049250313e-16f;  // np.spacing(1)
    float local = 0.0f;
    for (int idx = tid; idx < NB * NC * NC; idx += FT) {
        const int b = idx / (NC * NC);
        const int r = idx - b * NC * NC;
        const int i = r / NC;
        const int k = r - i * NC;
        const float* Sb = S + b * NC * 20;
        const float cnt_i = Sb[i * 20 + 19];
        const float cnt_k = Sb[k * 20 + 19];
        const float alpha = (cnt_i > 0.0f) ? Sb[i * 20 + i] / cnt_i : 0.0f;
        const float beta = (cnt_k > 0.0f) ? 1.0f - Sb[k * 20 + i] / cnt_k : 0.0f;
        local += logf(0.5f * (alpha + beta + eps));
    }

    #pragma unroll
    for (int off = 32; off > 0; off >>= 1) local += __shfl_down(local, off);
    if ((tid & 63) == 0) wsum[tid >> 6] = local;
    __syncthreads();
    if (tid == 0) {
        float t = 0.0f;
        #pragma unroll
        for (int w = 0; w < FT / 64; ++w) t += wsum[w];
        out[0] = -0.5f * t / (float)NB;
    }
}

extern "C" void kernel_launch(void* const* d_in, const int* in_sizes, int n_in,
                              void* d_out, int out_size, void* d_ws, size_t ws_size,
                              hipStream_t stream) {
    const float* seg = (const float*)d_in[0];
    const int* tgt = (const int*)d_in[1];
    float* S_part = (float*)d_ws;  // 194,560 B; every slot written unconditionally

    dim3 grid(NBLK);  // 1D; XCD-tile swizzle done in-kernel
    accum_kernel<<<grid, TPB, 0, stream>>>(seg, tgt, S_part);
    finalize_kernel<<<1, FT, 0, stream>>>(S_part, (float*)d_out);
}